// Round 8
// baseline (333.675 us; speedup 1.0000x reference)
//
#include <hip/hip_runtime.h>

#define FDIM   128
#define HEADS  4
#define ALPHA  0.2f
#define DMASK  0x03FFFFFF     // low 26 bits = dst
#define PT     4096           // partition tile (edges per block)
#define NBMAX  1568           // max fine buckets supported by static LDS

typedef float v2f __attribute__((ext_vector_type(2)));

__device__ __forceinline__ float readlane_f(float v, int lane) {
  return __int_as_float(__builtin_amdgcn_readlane(__float_as_int(v), lane));
}

// ------- per-node scores + bf16-pack of x (+ fine-bucket histogram slice) ----
__global__ __launch_bounds__(256) void score_kernel(
    const float* __restrict__ x, const float* __restrict__ W,
    const float* __restrict__ a, float* __restrict__ s_src,
    float* __restrict__ s_dst, unsigned int* __restrict__ xb,
    const int* __restrict__ src, int* __restrict__ hist,
    int E, int HB, int n) {
  __shared__ int h[NBMAX];
  int lane = threadIdx.x & 63;
  int node = (blockIdx.x << 2) + (threadIdx.x >> 6);
  if (node < n) {
    const float2* x2 = (const float2*)x;
    const float2* W2 = (const float2*)W;
    const float2* a2 = (const float2*)a;
    float2 xv = x2[(size_t)node * 64 + lane];

    // bf16 pack (round-to-nearest-even)
    unsigned int u0 = __float_as_uint(xv.x);
    unsigned int u1 = __float_as_uint(xv.y);
    u0 += 0x7fffu + ((u0 >> 16) & 1u);
    u1 += 0x7fffu + ((u1 >> 16) & 1u);
    xb[(size_t)node * 64 + lane] = (u0 >> 16) | (u1 & 0xffff0000u);

#pragma unroll
    for (int k = 0; k < HEADS; k++) {
      float2 wv = W2[k * 64 + lane];
      float hx = xv.x * wv.x, hy = xv.y * wv.y;
      float2 as_ = a2[k * 128 + lane];        // a[k, 0:F]
      float2 ad_ = a2[k * 128 + 64 + lane];   // a[k, F:2F]
      float rs = hx * as_.x + hy * as_.y;
      float rd = hx * ad_.x + hy * ad_.y;
#pragma unroll
      for (int off = 32; off > 0; off >>= 1) {
        rs += __shfl_down(rs, off);
        rd += __shfl_down(rd, off);
      }
      if (lane == 0) {
        s_src[node * HEADS + k] = rs;
        s_dst[node * HEADS + k] = rd;
      }
    }
  }

  // histogram slice: blocks [0, HB) each cover 8192 edges with LDS pre-agg
  int b = blockIdx.x;
  if (b < HB) {
    int t = threadIdx.x;
    int NB = (n + 63) >> 6;
    for (int i = t; i < NB; i += 256) h[i] = 0;
    __syncthreads();
    int base = b * 8192;
#pragma unroll 4
    for (int j = 0; j < 32; j++) {
      int i = base + j * 256 + t;
      if (i < E) atomicAdd(&h[src[i] >> 6], 1);
    }
    __syncthreads();
    for (int i = t; i < NB; i += 256)
      if (h[i]) atomicAdd(&hist[i], h[i]);
  }
}

// ---------------- exclusive scan of NB (<=2048) bucket counts: 1 block -------
__global__ __launch_bounds__(256) void scan_kernel(const int* __restrict__ hist,
                                                   int* __restrict__ fine_ptr,
                                                   int* __restrict__ cursor,
                                                   int NB, int E) {
  __shared__ int lds[256];
  int t = threadIdx.x;
  int loc[8];
  int s = 0;
#pragma unroll
  for (int j = 0; j < 8; j++) {
    int idx = t * 8 + j;
    loc[j] = (idx < NB) ? hist[idx] : 0;
    s += loc[j];
  }
  lds[t] = s;
  __syncthreads();
  for (int off = 1; off < 256; off <<= 1) {
    int xv = (t >= off) ? lds[t - off] : 0;
    __syncthreads();
    lds[t] += xv;
    __syncthreads();
  }
  int run = lds[t] - s;   // exclusive prefix of this thread's segment
#pragma unroll
  for (int j = 0; j < 8; j++) {
    int idx = t * 8 + j;
    if (idx < NB) {
      fine_ptr[idx] = run;
      cursor[idx]   = run;
    }
    run += loc[j];
  }
  if (t == 0) fine_ptr[NB] = E;
}

// ---------------- partition: tile-sort 4096 edges by fine bucket in LDS ------
__global__ __launch_bounds__(256) void partition_kernel(
    const int* __restrict__ src, const int* __restrict__ dst,
    const float* __restrict__ adj, int* __restrict__ cursor,
    int2* __restrict__ ebuf, int E, int NB) {
  __shared__ int h[NBMAX];
  __shared__ int sc[NBMAX];
  __shared__ int bg[NBMAX];
  __shared__ unsigned short keyarr[PT];
  __shared__ int2 es[PT];
  __shared__ int lds[256];

  int t = threadIdx.x;
  int base = blockIdx.x * PT;
  for (int i = t; i < NB; i += 256) h[i] = 0;
  __syncthreads();

  int ssrc[16];
#pragma unroll
  for (int j = 0; j < 16; j++) {
    int i = base + j * 256 + t;
    ssrc[j] = (i < E) ? src[i] : -1;
    if (ssrc[j] >= 0) atomicAdd(&h[ssrc[j] >> 6], 1);
  }
  __syncthreads();

  int loc[8];
  int s = 0;
#pragma unroll
  for (int j = 0; j < 8; j++) {
    int idx = t * 8 + j;
    loc[j] = (idx < NB) ? h[idx] : 0;
    s += loc[j];
  }
  lds[t] = s;
  __syncthreads();
  for (int off = 1; off < 256; off <<= 1) {
    int xv = (t >= off) ? lds[t - off] : 0;
    __syncthreads();
    lds[t] += xv;
    __syncthreads();
  }
  int run = lds[t] - s;
#pragma unroll
  for (int j = 0; j < 8; j++) {
    int idx = t * 8 + j;
    if (idx < NB) sc[idx] = run;
    run += loc[j];
  }
  __syncthreads();

  for (int i = t; i < NB; i += 256)
    if (h[i]) bg[i] = atomicAdd(&cursor[i], h[i]);
  __syncthreads();

#pragma unroll
  for (int j = 0; j < 16; j++) {
    if (ssrc[j] >= 0) {
      int i = base + j * 256 + t;
      int k = ssrc[j] >> 6;
      int slot = atomicAdd(&sc[k], 1);
      int2 pk;
      pk.x = (int)(((unsigned)(ssrc[j] & 63) << 26) | (unsigned)dst[i]);
      pk.y = __float_as_int(adj[i]);
      es[slot] = pk;
      keyarr[slot] = (unsigned short)k;
    }
  }
  __syncthreads();

  int tc = E - base; if (tc > PT) tc = PT;
  for (int s2 = t; s2 < tc; s2 += 256) {
    int k = keyarr[s2];
    int rank = s2 - (sc[k] - h[k]);
    ebuf[bg[k] + rank] = es[s2];
  }
}

// ---------------- aggregate: one block per 64-node bucket --------------------
// Per-node pipeline: half-wave pair gather — one dwordx2 instruction loads TWO
// edges' bf16 rows (lanes 0..31 -> edge 2j, lanes 32..63 -> edge 2j+1; each
// lane holds 4 features).  Halves merge via shfl_xor(32) in the epilogue.
// Padding invariant: slots >= cn carry pk={0,0} -> ev=0 and dst=0, so padded
// fmacs add exactly 0 (row 0 load is cached).
__global__ __launch_bounds__(256, 4) void aggregate_kernel(
    const unsigned int* __restrict__ xb, const float* __restrict__ W,
    const float* __restrict__ s_src, const float* __restrict__ s_dst,
    const int* __restrict__ fine_ptr, const int2* __restrict__ ebuf,
    float* __restrict__ out, int n) {
  __shared__ int2  es[2048];
  __shared__ float evbuf[4][64];
  __shared__ int   dvbuf[4][16];
  __shared__ int   nbeg[65];
  __shared__ int   nrun[64];
  __shared__ int   h[64];

  int t = threadIdx.x, b = blockIdx.x;
  int lane = t & 63, wid = t >> 6;
  int beg = fine_ptr[b];
  int L   = fine_ptr[b + 1] - beg;

  if (t < 64) h[t] = 0;
  __syncthreads();
  for (int i = t; i < L; i += 256)
    atomicAdd(&h[(unsigned)ebuf[beg + i].x >> 26], 1);
  __syncthreads();
  if (t < 64) {   // wave-0 shfl inclusive scan of 64 counters
    int v = h[t];
#pragma unroll
    for (int off = 1; off < 64; off <<= 1) {
      int u = __shfl_up(v, off);
      if (lane >= off) v += u;
    }
    nbeg[t + 1] = v;
    nrun[t] = v - h[t];
    if (t == 0) nbeg[0] = 0;
  }
  __syncthreads();
  for (int i = t; i < L; i += 256) {
    int2 pk = ebuf[beg + i];
    int kk = (unsigned)pk.x >> 26;
    int slot = atomicAdd(&nrun[kk], 1);
    es[slot] = pk;
  }
  __syncthreads();

  int e = lane >> 2;                   // edge slot 0..15
  int k = lane & 3;                    // head
  int half = lane >> 5;                // 0: edge 2j, 1: edge 2j+1
  int fl = lane & 31;                  // feature-lane: owns features fl*4..fl*4+3

  for (int ni = 0; ni < 16; ni++) {
    int nl = wid * 16 + ni;
    int node = (b << 6) + nl;
    if (node >= n) break;              // wave-uniform
    int eb = nbeg[nl], cnt = nbeg[nl + 1] - eb;
    float ssrc_k = s_src[node * HEADS + k];

    v2f aA0{0.f,0.f}, aA1{0.f,0.f}, aA2{0.f,0.f}, aA3{0.f,0.f};  // features fl*4, fl*4+1
    v2f aB0{0.f,0.f}, aB1{0.f,0.f}, aB2{0.f,0.f}, aB3{0.f,0.f};  // features fl*4+2, fl*4+3
    float rsum = 0.f;

    auto pair_one = [&](int j) {
      int dsel = dvbuf[wid][2 * j + half];
      uint2 xw = *(const uint2*)(xb + ((unsigned)dsel << 6) + (fl << 1));
      const float4 s4 = *(const float4*)&evbuf[wid][(2 * j + half) * 4];
      v2f x01, x23;
      x01.x = __uint_as_float(xw.x << 16);
      x01.y = __uint_as_float(xw.x & 0xffff0000u);
      x23.x = __uint_as_float(xw.y << 16);
      x23.y = __uint_as_float(xw.y & 0xffff0000u);
      aA0 += s4.x * x01; aB0 += s4.x * x23;
      aA1 += s4.y * x01; aB1 += s4.y * x23;
      aA2 += s4.z * x01; aB2 += s4.z * x23;
      aA3 += s4.w * x01; aB3 += s4.w * x23;
    };

    int c = 0;
    while (c < cnt) {
      int cn = cnt - c; if (cn > 16) cn = 16;
      int2 pk{0, 0};
      if (e < cn) pk = es[eb + c + e];
      int dv = pk.x & DMASK;
      float s = ssrc_k + s_dst[dv * HEADS + k];
      s = (s >= 0.f) ? s : ALPHA * s;
      float ev = __expf(s) * __int_as_float(pk.y);   // padded slots: adj=0 -> 0
      rsum += ev;
      evbuf[wid][lane] = ev;             // wave-private; in-order DS pipe
      if (k == 0) dvbuf[wid][e] = dv;

      if (cn == 16) {
        // full burst: 8 pair-gathers (16 edges) in flight
        int dsl[8];
        uint2 xw[8];
#pragma unroll
        for (int j = 0; j < 8; j++) dsl[j] = dvbuf[wid][2 * j + half];
#pragma unroll
        for (int j = 0; j < 8; j++)
          xw[j] = *(const uint2*)(xb + ((unsigned)dsl[j] << 6) + (fl << 1));
#pragma unroll
        for (int j = 0; j < 8; j++) {
          const float4 s4 = *(const float4*)&evbuf[wid][(2 * j + half) * 4];
          v2f x01, x23;
          x01.x = __uint_as_float(xw[j].x << 16);
          x01.y = __uint_as_float(xw[j].x & 0xffff0000u);
          x23.x = __uint_as_float(xw[j].y << 16);
          x23.y = __uint_as_float(xw[j].y & 0xffff0000u);
          aA0 += s4.x * x01; aB0 += s4.x * x23;
          aA1 += s4.y * x01; aB1 += s4.y * x23;
          aA2 += s4.z * x01; aB2 += s4.z * x23;
          aA3 += s4.w * x01; aB3 += s4.w * x23;
        }
      } else {
        int npair = (cn + 1) >> 1;
        for (int j = 0; j < npair; j++) pair_one(j);
      }
      c += 16;
    }

    // rowsum per head
    rsum += __shfl_xor(rsum, 4);
    rsum += __shfl_xor(rsum, 8);
    rsum += __shfl_xor(rsum, 16);
    rsum += __shfl_xor(rsum, 32);
    float r0 = readlane_f(rsum, 0), r1 = readlane_f(rsum, 1);
    float r2 = readlane_f(rsum, 2), r3 = readlane_f(rsum, 3);

    // merge halves (features align between lane and lane^32)
    aA0.x += __shfl_xor(aA0.x, 32); aA0.y += __shfl_xor(aA0.y, 32);
    aB0.x += __shfl_xor(aB0.x, 32); aB0.y += __shfl_xor(aB0.y, 32);
    aA1.x += __shfl_xor(aA1.x, 32); aA1.y += __shfl_xor(aA1.y, 32);
    aB1.x += __shfl_xor(aB1.x, 32); aB1.y += __shfl_xor(aB1.y, 32);
    aA2.x += __shfl_xor(aA2.x, 32); aA2.y += __shfl_xor(aA2.y, 32);
    aB2.x += __shfl_xor(aB2.x, 32); aB2.y += __shfl_xor(aB2.y, 32);
    aA3.x += __shfl_xor(aA3.x, 32); aA3.y += __shfl_xor(aA3.y, 32);
    aB3.x += __shfl_xor(aB3.x, 32); aB3.y += __shfl_xor(aB3.y, 32);

    if (lane < 32) {
      float4 o{0.f, 0.f, 0.f, 0.f};
      float hx;
      const float* Wp = W;
#define EPI(ACCA, ACCB, RR, KK)                                          \
      {                                                                  \
        const float4 wv = *(const float4*)&Wp[KK * FDIM + (fl << 2)];    \
        float inv = 1.0f / RR;                                           \
        hx = wv.x * ACCA.x * inv; o.x += (hx > 0.f) ? hx : expm1f(hx);   \
        hx = wv.y * ACCA.y * inv; o.y += (hx > 0.f) ? hx : expm1f(hx);   \
        hx = wv.z * ACCB.x * inv; o.z += (hx > 0.f) ? hx : expm1f(hx);   \
        hx = wv.w * ACCB.y * inv; o.w += (hx > 0.f) ? hx : expm1f(hx);   \
      }
      EPI(aA0, aB0, r0, 0)
      EPI(aA1, aB1, r1, 1)
      EPI(aA2, aB2, r2, 2)
      EPI(aA3, aB3, r3, 3)
#undef EPI
      o.x *= 0.25f; o.y *= 0.25f; o.z *= 0.25f; o.w *= 0.25f;
      *(float4*)&out[(size_t)node * FDIM + (fl << 2)] = o;
    }
  }
}

extern "C" void kernel_launch(void* const* d_in, const int* in_sizes, int n_in,
                              void* d_out, int out_size, void* d_ws, size_t ws_size,
                              hipStream_t stream) {
  const float* x   = (const float*)d_in[0];
  const int*   edg = (const int*)d_in[1];
  const float* adj = (const float*)d_in[2];
  const float* W   = (const float*)d_in[3];
  const float* a   = (const float*)d_in[4];
  float* out = (float*)d_out;

  int E = in_sizes[2];
  int n = in_sizes[0] / FDIM;
  const int* src = edg;
  const int* dst = edg + E;
  int NB = (n + 63) >> 6;              // fine buckets of 64 nodes (<= NBMAX)
  int HB = (E + 8191) / 8192;          // histogram tiles

  auto align = [](size_t v) { return (v + 255) & ~(size_t)255; };
  char* ws = (char*)d_ws;
  int*   fine_ptr = (int*)ws;          ws += align((size_t)(NB + 1) * 4);
  int*   cursor   = (int*)ws;          ws += align((size_t)NB * 4);
  int*   hist     = (int*)ws;          ws += align((size_t)NB * 4);
  int2*  ebuf     = (int2*)ws;         ws += align((size_t)E * 8);
  float* s_src    = (float*)ws;        ws += align((size_t)n * HEADS * 4);
  float* s_dst    = (float*)ws;        ws += align((size_t)n * HEADS * 4);
  unsigned int* xb = (unsigned int*)ws; ws += align((size_t)n * 64 * 4);

  hipMemsetAsync(hist, 0, (size_t)NB * 4, stream);

  score_kernel<<<(n + 3) / 4, 256, 0, stream>>>(x, W, a, s_src, s_dst, xb,
                                                src, hist, E, HB, n);
  scan_kernel<<<1, 256, 0, stream>>>(hist, fine_ptr, cursor, NB, E);
  partition_kernel<<<(E + PT - 1) / PT, 256, 0, stream>>>(src, dst, adj, cursor,
                                                          ebuf, E, NB);
  aggregate_kernel<<<NB, 256, 0, stream>>>(xb, W, s_src, s_dst, fine_ptr,
                                           ebuf, out, n);
}

// Round 9
// 320.569 us; speedup vs baseline: 1.0409x; 1.0409x over previous
//
#include <hip/hip_runtime.h>

#define FDIM   128
#define HEADS  4
#define ALPHA  0.2f
#define DMASK  0x03FFFFFF     // low 26 bits = dst
#define PT     4096           // partition tile (edges per block)
#define NBMAX  1568           // max fine buckets supported by static LDS

typedef float v2f __attribute__((ext_vector_type(2)));

__device__ __forceinline__ float readlane_f(float v, int lane) {
  return __int_as_float(__builtin_amdgcn_readlane(__float_as_int(v), lane));
}

// ------- per-node scores + bf16-pack of x (+ fine-bucket histogram slice) ----
__global__ __launch_bounds__(256) void score_kernel(
    const float* __restrict__ x, const float* __restrict__ W,
    const float* __restrict__ a, float* __restrict__ s_src,
    float* __restrict__ s_dst, unsigned int* __restrict__ xb,
    const int* __restrict__ src, int* __restrict__ hist,
    int E, int HB, int n) {
  __shared__ int h[NBMAX];
  int lane = threadIdx.x & 63;
  int node = (blockIdx.x << 2) + (threadIdx.x >> 6);
  if (node < n) {
    const float2* x2 = (const float2*)x;
    const float2* W2 = (const float2*)W;
    const float2* a2 = (const float2*)a;
    float2 xv = x2[(size_t)node * 64 + lane];

    // bf16 pack (round-to-nearest-even)
    unsigned int u0 = __float_as_uint(xv.x);
    unsigned int u1 = __float_as_uint(xv.y);
    u0 += 0x7fffu + ((u0 >> 16) & 1u);
    u1 += 0x7fffu + ((u1 >> 16) & 1u);
    xb[(size_t)node * 64 + lane] = (u0 >> 16) | (u1 & 0xffff0000u);

#pragma unroll
    for (int k = 0; k < HEADS; k++) {
      float2 wv = W2[k * 64 + lane];
      float hx = xv.x * wv.x, hy = xv.y * wv.y;
      float2 as_ = a2[k * 128 + lane];        // a[k, 0:F]
      float2 ad_ = a2[k * 128 + 64 + lane];   // a[k, F:2F]
      float rs = hx * as_.x + hy * as_.y;
      float rd = hx * ad_.x + hy * ad_.y;
#pragma unroll
      for (int off = 32; off > 0; off >>= 1) {
        rs += __shfl_down(rs, off);
        rd += __shfl_down(rd, off);
      }
      if (lane == 0) {
        s_src[node * HEADS + k] = rs;
        s_dst[node * HEADS + k] = rd;
      }
    }
  }

  // histogram slice: blocks [0, HB) each cover 8192 edges with LDS pre-agg
  int b = blockIdx.x;
  if (b < HB) {
    int t = threadIdx.x;
    int NB = (n + 63) >> 6;
    for (int i = t; i < NB; i += 256) h[i] = 0;
    __syncthreads();
    int base = b * 8192;
#pragma unroll 4
    for (int j = 0; j < 32; j++) {
      int i = base + j * 256 + t;
      if (i < E) atomicAdd(&h[src[i] >> 6], 1);
    }
    __syncthreads();
    for (int i = t; i < NB; i += 256)
      if (h[i]) atomicAdd(&hist[i], h[i]);
  }
}

// ---------------- exclusive scan of NB (<=2048) bucket counts: 1 block -------
__global__ __launch_bounds__(256) void scan_kernel(const int* __restrict__ hist,
                                                   int* __restrict__ fine_ptr,
                                                   int* __restrict__ cursor,
                                                   int NB, int E) {
  __shared__ int lds[256];
  int t = threadIdx.x;
  int loc[8];
  int s = 0;
#pragma unroll
  for (int j = 0; j < 8; j++) {
    int idx = t * 8 + j;
    loc[j] = (idx < NB) ? hist[idx] : 0;
    s += loc[j];
  }
  lds[t] = s;
  __syncthreads();
  for (int off = 1; off < 256; off <<= 1) {
    int xv = (t >= off) ? lds[t - off] : 0;
    __syncthreads();
    lds[t] += xv;
    __syncthreads();
  }
  int run = lds[t] - s;   // exclusive prefix of this thread's segment
#pragma unroll
  for (int j = 0; j < 8; j++) {
    int idx = t * 8 + j;
    if (idx < NB) {
      fine_ptr[idx] = run;
      cursor[idx]   = run;
    }
    run += loc[j];
  }
  if (t == 0) fine_ptr[NB] = E;
}

// ---------------- partition: tile-sort 4096 edges by fine bucket in LDS ------
__global__ __launch_bounds__(256) void partition_kernel(
    const int* __restrict__ src, const int* __restrict__ dst,
    const float* __restrict__ adj, int* __restrict__ cursor,
    int2* __restrict__ ebuf, int E, int NB) {
  __shared__ int h[NBMAX];
  __shared__ int sc[NBMAX];
  __shared__ int bg[NBMAX];
  __shared__ unsigned short keyarr[PT];
  __shared__ int2 es[PT];
  __shared__ int lds[256];

  int t = threadIdx.x;
  int base = blockIdx.x * PT;
  for (int i = t; i < NB; i += 256) h[i] = 0;
  __syncthreads();

  int ssrc[16];
#pragma unroll
  for (int j = 0; j < 16; j++) {
    int i = base + j * 256 + t;
    ssrc[j] = (i < E) ? src[i] : -1;
    if (ssrc[j] >= 0) atomicAdd(&h[ssrc[j] >> 6], 1);
  }
  __syncthreads();

  int loc[8];
  int s = 0;
#pragma unroll
  for (int j = 0; j < 8; j++) {
    int idx = t * 8 + j;
    loc[j] = (idx < NB) ? h[idx] : 0;
    s += loc[j];
  }
  lds[t] = s;
  __syncthreads();
  for (int off = 1; off < 256; off <<= 1) {
    int xv = (t >= off) ? lds[t - off] : 0;
    __syncthreads();
    lds[t] += xv;
    __syncthreads();
  }
  int run = lds[t] - s;
#pragma unroll
  for (int j = 0; j < 8; j++) {
    int idx = t * 8 + j;
    if (idx < NB) sc[idx] = run;
    run += loc[j];
  }
  __syncthreads();

  for (int i = t; i < NB; i += 256)
    if (h[i]) bg[i] = atomicAdd(&cursor[i], h[i]);
  __syncthreads();

#pragma unroll
  for (int j = 0; j < 16; j++) {
    if (ssrc[j] >= 0) {
      int i = base + j * 256 + t;
      int k = ssrc[j] >> 6;
      int slot = atomicAdd(&sc[k], 1);
      int2 pk;
      pk.x = (int)(((unsigned)(ssrc[j] & 63) << 26) | (unsigned)dst[i]);
      pk.y = __float_as_int(adj[i]);
      es[slot] = pk;
      keyarr[slot] = (unsigned short)k;
    }
  }
  __syncthreads();

  int tc = E - base; if (tc > PT) tc = PT;
  for (int s2 = t; s2 < tc; s2 += 256) {
    int k = keyarr[s2];
    int rank = s2 - (sc[k] - h[k]);
    ebuf[bg[k] + rank] = es[s2];
  }
}

// ---------------- aggregate: one block per 64-node bucket --------------------
// Chunk pipeline: issue s_dst gather + ALL 16 row gathers first, THEN do the
// exp/evbuf phase while rows are in flight, then fma-drain.  Overlaps the two
// long-latency random-gather phases that were previously serialized.
// Padding invariant: slots >= cn carry pk={0,0} -> ev=0 and dst=0, so padded
// fmacs add exactly 0 (row 0 load is cached).
__global__ __launch_bounds__(256, 4) void aggregate_kernel(
    const unsigned int* __restrict__ xb, const float* __restrict__ W,
    const float* __restrict__ s_src, const float* __restrict__ s_dst,
    const int* __restrict__ fine_ptr, const int2* __restrict__ ebuf,
    float* __restrict__ out, int n) {
  __shared__ int2  es[2048];
  __shared__ float evbuf[4][64];
  __shared__ int   nbeg[65];
  __shared__ int   nrun[64];
  __shared__ int   h[64];

  int t = threadIdx.x, b = blockIdx.x;
  int lane = t & 63, wid = t >> 6;
  int beg = fine_ptr[b];
  int L   = fine_ptr[b + 1] - beg;

  if (t < 64) h[t] = 0;
  __syncthreads();
  for (int i = t; i < L; i += 256)
    atomicAdd(&h[(unsigned)ebuf[beg + i].x >> 26], 1);
  __syncthreads();
  if (t < 64) {   // wave-0 shfl inclusive scan of 64 counters
    int v = h[t];
#pragma unroll
    for (int off = 1; off < 64; off <<= 1) {
      int u = __shfl_up(v, off);
      if (lane >= off) v += u;
    }
    nbeg[t + 1] = v;
    nrun[t] = v - h[t];
    if (t == 0) nbeg[0] = 0;
  }
  __syncthreads();
  for (int i = t; i < L; i += 256) {
    int2 pk = ebuf[beg + i];
    int kk = (unsigned)pk.x >> 26;
    int slot = atomicAdd(&nrun[kk], 1);
    es[slot] = pk;
  }
  __syncthreads();

  int e = lane >> 2;                   // edge slot 0..15
  int k = lane & 3;                    // head

  for (int ni = 0; ni < 16; ni++) {
    int nl = wid * 16 + ni;
    int node = (b << 6) + nl;
    if (node >= n) break;              // wave-uniform
    int eb = nbeg[nl], cnt = nbeg[nl + 1] - eb;
    float ssrc_k = s_src[node * HEADS + k];

    v2f acc0{0.f,0.f}, acc1{0.f,0.f}, acc2{0.f,0.f}, acc3{0.f,0.f};
    float rsum = 0.f;

    int c = 0;
    while (c < cnt) {
      int cn = cnt - c; if (cn > 16) cn = 16;
      int2 pk{0, 0};
      if (e < cn) pk = es[eb + c + e];
      int dv = pk.x & DMASK;

      // ---- issue ALL long-latency loads up front ----
      float sdv = s_dst[dv * HEADS + k];          // score gather (in flight)
      int dd[16];
#pragma unroll
      for (int j = 0; j < 16; j++)
        dd[j] = __builtin_amdgcn_readlane(pk.x, j * 4) & DMASK;
      unsigned int xw[16];
#pragma unroll
      for (int j = 0; j < 16; j++)
        xw[j] = xb[((unsigned)dd[j] << 6) + lane];  // 16 row gathers in flight

      // ---- ev phase (waits only on sdv; rows still flying) ----
      float s = ssrc_k + sdv;
      s = (s >= 0.f) ? s : ALPHA * s;
      float ev = __expf(s) * __int_as_float(pk.y);  // padded slots: adj=0 -> 0
      rsum += ev;
      evbuf[wid][lane] = ev;             // wave-private; in-order DS pipe

      // ---- fma drain ----
#pragma unroll
      for (int j = 0; j < 16; j++) {
        const float4 s4 = *(const float4*)&evbuf[wid][j * 4];
        v2f xv;
        xv.x = __uint_as_float(xw[j] << 16);
        xv.y = __uint_as_float(xw[j] & 0xffff0000u);
        acc0 += s4.x * xv;
        acc1 += s4.y * xv;
        acc2 += s4.z * xv;
        acc3 += s4.w * xv;
      }
      c += 16;
    }

    // rowsum per head
    rsum += __shfl_xor(rsum, 4);
    rsum += __shfl_xor(rsum, 8);
    rsum += __shfl_xor(rsum, 16);
    rsum += __shfl_xor(rsum, 32);
    float r0 = readlane_f(rsum, 0), r1 = readlane_f(rsum, 1);
    float r2 = readlane_f(rsum, 2), r3 = readlane_f(rsum, 3);

    const float2* W2 = (const float2*)W;
    float2 o{0.f, 0.f};
    float hx, hy;
    {
      float2 wv = W2[0 * 64 + lane];
      hx = wv.x * acc0.x / r0; hy = wv.y * acc0.y / r0;
      o.x += (hx > 0.f) ? hx : expm1f(hx); o.y += (hy > 0.f) ? hy : expm1f(hy);
    }
    {
      float2 wv = W2[1 * 64 + lane];
      hx = wv.x * acc1.x / r1; hy = wv.y * acc1.y / r1;
      o.x += (hx > 0.f) ? hx : expm1f(hx); o.y += (hy > 0.f) ? hy : expm1f(hy);
    }
    {
      float2 wv = W2[2 * 64 + lane];
      hx = wv.x * acc2.x / r2; hy = wv.y * acc2.y / r2;
      o.x += (hx > 0.f) ? hx : expm1f(hx); o.y += (hy > 0.f) ? hy : expm1f(hy);
    }
    {
      float2 wv = W2[3 * 64 + lane];
      hx = wv.x * acc3.x / r3; hy = wv.y * acc3.y / r3;
      o.x += (hx > 0.f) ? hx : expm1f(hx); o.y += (hy > 0.f) ? hy : expm1f(hy);
    }
    o.x *= 0.25f; o.y *= 0.25f;
    ((float2*)out)[(size_t)node * 64 + lane] = o;
  }
}

extern "C" void kernel_launch(void* const* d_in, const int* in_sizes, int n_in,
                              void* d_out, int out_size, void* d_ws, size_t ws_size,
                              hipStream_t stream) {
  const float* x   = (const float*)d_in[0];
  const int*   edg = (const int*)d_in[1];
  const float* adj = (const float*)d_in[2];
  const float* W   = (const float*)d_in[3];
  const float* a   = (const float*)d_in[4];
  float* out = (float*)d_out;

  int E = in_sizes[2];
  int n = in_sizes[0] / FDIM;
  const int* src = edg;
  const int* dst = edg + E;
  int NB = (n + 63) >> 6;              // fine buckets of 64 nodes (<= NBMAX)
  int HB = (E + 8191) / 8192;          // histogram tiles

  auto align = [](size_t v) { return (v + 255) & ~(size_t)255; };
  char* ws = (char*)d_ws;
  int*   fine_ptr = (int*)ws;          ws += align((size_t)(NB + 1) * 4);
  int*   cursor   = (int*)ws;          ws += align((size_t)NB * 4);
  int*   hist     = (int*)ws;          ws += align((size_t)NB * 4);
  int2*  ebuf     = (int2*)ws;         ws += align((size_t)E * 8);
  float* s_src    = (float*)ws;        ws += align((size_t)n * HEADS * 4);
  float* s_dst    = (float*)ws;        ws += align((size_t)n * HEADS * 4);
  unsigned int* xb = (unsigned int*)ws; ws += align((size_t)n * 64 * 4);

  hipMemsetAsync(hist, 0, (size_t)NB * 4, stream);

  score_kernel<<<(n + 3) / 4, 256, 0, stream>>>(x, W, a, s_src, s_dst, xb,
                                                src, hist, E, HB, n);
  scan_kernel<<<1, 256, 0, stream>>>(hist, fine_ptr, cursor, NB, E);
  partition_kernel<<<(E + PT - 1) / PT, 256, 0, stream>>>(src, dst, adj, cursor,
                                                          ebuf, E, NB);
  aggregate_kernel<<<NB, 256, 0, stream>>>(xb, W, s_src, s_dst, fine_ptr,
                                           ebuf, out, n);
}